// Round 3
// baseline (97.305 us; speedup 1.0000x reference)
//
#include <hip/hip_runtime.h>

// Problem constants (from setup_inputs): N=32, D=32, S=32, B=15, m=128
#define N_ 32
#define D_ 32
#define S_ 32
#define M_ 128
#define MM_ (M_ * M_)
#define INV_M (1.0f / 128.0f)
#define INV_M2 (1.0f / (128.0f * 128.0f))

// Workspace layout (float offsets). Total ~790,528 floats = ~3.02 MiB.
#define WS_ROWSUM  0         // [N*D][128]
#define WS_COLSUM  131072    // [N*D][128]
#define WS_DIAG    262144    // [N*D][128]
#define WS_SUMDIAG 393216    // [N*D]
#define WS_TOT     394240    // [N*D]
#define WS_RV      395264    // [N*S][128]  (includes K + bias)
#define WS_CV      526336    // [N*S][128]
#define WS_DG      657408    // [N*S][128]  (includes diag_bias)
#define WS_WPACK   788480    // float2 [D][S] = (c_op10, c_op11)

// ---------------- Kernel A: per-(n,d) reductions ----------------
__global__ __launch_bounds__(256) void eq2_reduce(const float* __restrict__ x,
                                                  float* __restrict__ ws) {
    int nd = blockIdx.x;              // n*D + d
    int t  = threadIdx.x;
    int g  = t >> 5;                  // row group 0..7 (16 rows each)
    int j4 = t & 31;                  // float4 column group (cols 4*j4..4*j4+3)

    const float4* xp = (const float4*)(x + (size_t)nd * MM_);

    float* rowsum  = ws + WS_ROWSUM;
    float* colsum  = ws + WS_COLSUM;
    float* diag    = ws + WS_DIAG;
    float* sumdiag = ws + WS_SUMDIAG;
    float* tot     = ws + WS_TOT;

    float4 cs = {0.f, 0.f, 0.f, 0.f};
    float dsum = 0.f, ttot = 0.f;

    for (int r = 0; r < 16; ++r) {
        int i = g * 16 + r;
        float4 v = xp[i * 32 + j4];
        cs.x += v.x; cs.y += v.y; cs.z += v.z; cs.w += v.w;
        float rp = v.x + v.y + v.z + v.w;
        ttot += rp;
        int c = i - 4 * j4;           // diagonal element if 0..3
        if (c >= 0 && c < 4) {
            float dv = (c == 0) ? v.x : (c == 1) ? v.y : (c == 2) ? v.z : v.w;
            diag[nd * M_ + i] = dv;
            dsum += dv;
        }
        // row sum: reduce over the 32 lanes covering this row
        float rs = rp;
        for (int msk = 1; msk < 32; msk <<= 1) rs += __shfl_xor(rs, msk, 64);
        if ((t & 31) == 0) rowsum[nd * M_ + i] = rs;
    }

    __shared__ float4 cs_lds[8][32];
    __shared__ float  red[2][4];
    cs_lds[g][j4] = cs;

    // block-reduce dsum / ttot (full 64-lane wave, then across 4 waves)
    for (int msk = 1; msk < 64; msk <<= 1) {
        dsum += __shfl_xor(dsum, msk, 64);
        ttot += __shfl_xor(ttot, msk, 64);
    }
    int wave = t >> 6, lane = t & 63;
    if (lane == 0) { red[0][wave] = dsum; red[1][wave] = ttot; }
    __syncthreads();

    if (t < 32) {
        float4 a = cs_lds[0][t];
        for (int gg = 1; gg < 8; ++gg) {
            float4 b = cs_lds[gg][t];
            a.x += b.x; a.y += b.y; a.z += b.z; a.w += b.w;
        }
        ((float4*)(colsum + nd * M_))[t] = a;
    }
    if (t == 0) {
        sumdiag[nd] = red[0][0] + red[0][1] + red[0][2] + red[0][3];
        tot[nd]     = red[1][0] + red[1][1] + red[1][2] + red[1][3];
    }
}

// ---------------- Kernel B: contract reductions with coefs over d ----------------
// coefs layout: [d][s][b], b in 0..14 -> op1..op15
__global__ __launch_bounds__(128) void eq2_combine(const float* __restrict__ coefs,
                                                   const float* __restrict__ bias,
                                                   const float* __restrict__ diag_bias,
                                                   float* __restrict__ ws) {
    int b = blockIdx.x;
    int n = b >> 5, s = b & 31;
    int i = threadIdx.x;              // 0..127

    const float* rowsum  = ws + WS_ROWSUM;
    const float* colsum  = ws + WS_COLSUM;
    const float* diag    = ws + WS_DIAG;
    const float* sumdiag = ws + WS_SUMDIAG;
    const float* tot     = ws + WS_TOT;

    float rv = 0.f, cv = 0.f, dg = 0.f, kk = 0.f;
    for (int d = 0; d < D_; ++d) {
        const float* cf = coefs + (d * S_ + s) * 15;   // uniform -> s_load
        float rs = rowsum[(n * D_ + d) * M_ + i];
        float c2 = colsum[(n * D_ + d) * M_ + i];
        float dv = diag[(n * D_ + d) * M_ + i];
        float sd = sumdiag[n * D_ + d];
        float tt = tot[n * D_ + d];
        rv += (cf[5] * c2 + cf[6] * rs) * INV_M + cf[11] * dv;          // op6,7,12
        cv += (cf[7] * c2 + cf[8] * rs) * INV_M + cf[12] * dv;          // op8,9,13
        dg += cf[0] * dv + (cf[1] * sd + cf[2] * rs + cf[3] * c2) * INV_M
              + cf[4] * tt * INV_M2;                                    // op1..5
        kk += cf[13] * sd * INV_M + cf[14] * tt * INV_M2;               // op14,15
    }
    ws[WS_RV + (n * S_ + s) * M_ + i] = rv + kk + bias[s];
    ws[WS_CV + (n * S_ + s) * M_ + i] = cv;
    ws[WS_DG + (n * S_ + s) * M_ + i] = dg + diag_bias[s];

    // pack (c10, c11) once (blocks with n==0)
    if (n == 0 && i < D_) {
        const float* cf = coefs + (i * S_ + s) * 15;
        float2* wpack = (float2*)(ws + WS_WPACK);
        wpack[i * S_ + s] = make_float2(cf[9], cf[10]);
    }
}

// ---------------- Kernel C: dense part, transpose-free K-loop ----------------
// out[n,s] = Y + Z^T + rank-1, with Y = sum_d c10*X_d, Z = sum_d c11*X_d.
// Block owns symmetric tile pair {(ta_r,ta_c),(ta_c,ta_r)} of 16x16 tiles
// (diagonal tiles paired 2-at-a-time). K-loop: no LDS, no barriers, pure
// coalesced loads + FMA; Z transposed once in the epilogue via LDS.
__global__ __launch_bounds__(256, 3) void eq2_main(const float* __restrict__ x,
                                                   const float* __restrict__ ws,
                                                   float* __restrict__ out) {
    // XCD-chunked swizzle (round-robin blockIdx -> XCD): all 32 blocks of an n
    // run on one XCD back-to-back. Bijective over 1024 blocks.
    int lid = blockIdx.x;
    int n   = (lid & 7) + ((lid >> 8) << 3);
    int b   = (lid >> 3) & 31;

    // decode tile pair: b<28 -> off-diagonal pair (ti,tj), ti<tj; b>=28 -> two diagonal tiles
    int ta_r, ta_c, tb_r, tb_c, diagpair;
    if (b < 28) {
        int ti = 0, rem = b;
        while (rem >= 7 - ti) { rem -= 7 - ti; ++ti; }
        int tj = ti + 1 + rem;
        ta_r = ti; ta_c = tj; tb_r = tj; tb_c = ti; diagpair = 0;
    } else {
        int p = b - 28;
        ta_r = 2 * p; ta_c = 2 * p; tb_r = 2 * p + 1; tb_c = 2 * p + 1; diagpair = 1;
    }

    int t = threadIdx.x;
    int i = t >> 4;                   // 0..15
    int j = t & 15;                   // 0..15

    const float*  xn    = x + (size_t)n * (D_ * MM_);
    const float2* wpack = (const float2*)(ws + WS_WPACK);
    const float*  Rv    = ws + WS_RV;
    const float*  Cv    = ws + WS_CV;
    const float*  Dg    = ws + WS_DG;

    const float* pA = xn + (ta_r * 16 + i) * M_ + ta_c * 16 + j;
    const float* pB = xn + (tb_r * 16 + i) * M_ + tb_c * 16 + j;

    float Ya[S_], Za[S_], Yb[S_], Zb[S_];
#pragma unroll
    for (int s = 0; s < S_; ++s) { Ya[s] = 0.f; Za[s] = 0.f; Yb[s] = 0.f; Zb[s] = 0.f; }

    // software pipeline, depth 2, no barriers
    float a0 = pA[0], b0 = pB[0];
    float a1 = pA[MM_], b1 = pB[MM_];
    for (int d = 0; d < D_; ++d) {
        float a2, b2;
        if (d + 2 < D_) {
            a2 = pA[(size_t)(d + 2) * MM_];
            b2 = pB[(size_t)(d + 2) * MM_];
        }
        const float2* wd = wpack + d * S_;     // uniform -> s_load
#pragma unroll
        for (int s = 0; s < S_; ++s) {
            float2 cw = wd[s];
            Ya[s] = fmaf(cw.x, a0, Ya[s]);
            Za[s] = fmaf(cw.y, a0, Za[s]);
            Yb[s] = fmaf(cw.x, b0, Yb[s]);
            Zb[s] = fmaf(cw.y, b0, Zb[s]);
        }
        a0 = a1; b0 = b1; a1 = a2; b1 = b2;
    }

    // ---- epilogue: transpose Z via LDS (groups of 8 s), add rank-1, store ----
    __shared__ float tr[8][2][16][17];
    int giA = ta_r * 16 + i, gjA = ta_c * 16 + j;
    int giB = tb_r * 16 + i, gjB = tb_c * 16 + j;

    for (int g = 0; g < 4; ++g) {
        if (g) __syncthreads();       // previous group's reads done
#pragma unroll
        for (int ss = 0; ss < 8; ++ss) {
            int s = g * 8 + ss;
            // slot0 holds the Z whose transpose feeds out_a; slot1 -> out_b
            tr[ss][0][i][j] = diagpair ? Za[s] : Zb[s];
            tr[ss][1][i][j] = diagpair ? Zb[s] : Za[s];
        }
        __syncthreads();
#pragma unroll
        for (int ss = 0; ss < 8; ++ss) {
            int s = g * 8 + ss;
            int base = (n * S_ + s) * M_;
            float oA = Ya[s] + tr[ss][0][j][i] + Rv[base + giA] + Cv[base + gjA];
            float oB = Yb[s] + tr[ss][1][j][i] + Rv[base + giB] + Cv[base + gjB];
            if (diagpair && i == j) { oA += Dg[base + giA]; oB += Dg[base + giB]; }
            out[(size_t)base * M_ + giA * M_ + gjA] = oA;
            out[(size_t)base * M_ + giB * M_ + gjB] = oB;
        }
    }
}

extern "C" void kernel_launch(void* const* d_in, const int* in_sizes, int n_in,
                              void* d_out, int out_size, void* d_ws, size_t ws_size,
                              hipStream_t stream) {
    const float* x         = (const float*)d_in[0];
    const float* coefs     = (const float*)d_in[1];
    const float* bias      = (const float*)d_in[2];
    const float* diag_bias = (const float*)d_in[3];
    float* out = (float*)d_out;
    float* ws  = (float*)d_ws;   // needs ~3.1 MiB

    hipLaunchKernelGGL(eq2_reduce,  dim3(N_ * D_), dim3(256), 0, stream, x, ws);
    hipLaunchKernelGGL(eq2_combine, dim3(N_ * S_), dim3(128), 0, stream, coefs, bias, diag_bias, ws);
    hipLaunchKernelGGL(eq2_main,    dim3(1024), dim3(256), 0, stream, x, ws, out);
}

// Round 4
// 81.525 us; speedup vs baseline: 1.1936x; 1.1936x over previous
//
#include <hip/hip_runtime.h>

// Problem constants (from setup_inputs): N=32, D=32, S=32, B=15, m=128
#define N_ 32
#define D_ 32
#define S_ 32
#define M_ 128
#define MM_ (M_ * M_)
#define INV_M (1.0f / 128.0f)
#define INV_M2 (1.0f / (128.0f * 128.0f))

typedef float v2f __attribute__((ext_vector_type(2)));

// Workspace layout (float offsets). Total 790,528 floats = ~3.02 MiB.
#define WS_ROWSUM  0         // [N*D][128]
#define WS_COLSUM  131072    // [N*D][128]
#define WS_DIAG    262144    // [N*D][128]
#define WS_SUMDIAG 393216    // [N*D]
#define WS_TOT     394240    // [N*D]
#define WS_RV      395264    // [N*S][128]  (includes K + bias)
#define WS_CV      526336    // [N*S][128]
#define WS_DG      657408    // [N*S][128]  (includes diag_bias)
#define WS_W10     788480    // [D][S] c_op10  (s-contiguous rows, 128B aligned)
#define WS_W11     789504    // [D][S] c_op11

// ---------------- Kernel A: per-(n,d) reductions ----------------
__global__ __launch_bounds__(256) void eq2_reduce(const float* __restrict__ x,
                                                  float* __restrict__ ws) {
    int nd = blockIdx.x;              // n*D + d
    int t  = threadIdx.x;
    int g  = t >> 5;                  // row group 0..7 (16 rows each)
    int j4 = t & 31;                  // float4 column group

    const float4* xp = (const float4*)(x + (size_t)nd * MM_);

    float* rowsum  = ws + WS_ROWSUM;
    float* colsum  = ws + WS_COLSUM;
    float* diag    = ws + WS_DIAG;
    float* sumdiag = ws + WS_SUMDIAG;
    float* tot     = ws + WS_TOT;

    float4 cs = {0.f, 0.f, 0.f, 0.f};
    float dsum = 0.f, ttot = 0.f;

    for (int r = 0; r < 16; ++r) {
        int i = g * 16 + r;
        float4 v = xp[i * 32 + j4];
        cs.x += v.x; cs.y += v.y; cs.z += v.z; cs.w += v.w;
        float rp = v.x + v.y + v.z + v.w;
        ttot += rp;
        int c = i - 4 * j4;           // diagonal element if 0..3
        if (c >= 0 && c < 4) {
            float dv = (c == 0) ? v.x : (c == 1) ? v.y : (c == 2) ? v.z : v.w;
            diag[nd * M_ + i] = dv;
            dsum += dv;
        }
        float rs = rp;
        for (int msk = 1; msk < 32; msk <<= 1) rs += __shfl_xor(rs, msk, 64);
        if ((t & 31) == 0) rowsum[nd * M_ + i] = rs;
    }

    __shared__ float4 cs_lds[8][32];
    __shared__ float  red[2][4];
    cs_lds[g][j4] = cs;

    for (int msk = 1; msk < 64; msk <<= 1) {
        dsum += __shfl_xor(dsum, msk, 64);
        ttot += __shfl_xor(ttot, msk, 64);
    }
    int wave = t >> 6, lane = t & 63;
    if (lane == 0) { red[0][wave] = dsum; red[1][wave] = ttot; }
    __syncthreads();

    if (t < 32) {
        float4 a = cs_lds[0][t];
        for (int gg = 1; gg < 8; ++gg) {
            float4 b = cs_lds[gg][t];
            a.x += b.x; a.y += b.y; a.z += b.z; a.w += b.w;
        }
        ((float4*)(colsum + nd * M_))[t] = a;
    }
    if (t == 0) {
        sumdiag[nd] = red[0][0] + red[0][1] + red[0][2] + red[0][3];
        tot[nd]     = red[1][0] + red[1][1] + red[1][2] + red[1][3];
    }
}

// ---------------- Kernel B: contract reductions with coefs over d ----------------
__global__ __launch_bounds__(128) void eq2_combine(const float* __restrict__ coefs,
                                                   const float* __restrict__ bias,
                                                   const float* __restrict__ diag_bias,
                                                   float* __restrict__ ws) {
    int b = blockIdx.x;
    int n = b >> 5, s = b & 31;
    int i = threadIdx.x;              // 0..127

    const float* rowsum  = ws + WS_ROWSUM;
    const float* colsum  = ws + WS_COLSUM;
    const float* diag    = ws + WS_DIAG;
    const float* sumdiag = ws + WS_SUMDIAG;
    const float* tot     = ws + WS_TOT;

    float rv = 0.f, cv = 0.f, dg = 0.f, kk = 0.f;
    for (int d = 0; d < D_; ++d) {
        const float* cf = coefs + (d * S_ + s) * 15;   // uniform -> s_load
        float rs = rowsum[(n * D_ + d) * M_ + i];
        float c2 = colsum[(n * D_ + d) * M_ + i];
        float dv = diag[(n * D_ + d) * M_ + i];
        float sd = sumdiag[n * D_ + d];
        float tt = tot[n * D_ + d];
        rv += (cf[5] * c2 + cf[6] * rs) * INV_M + cf[11] * dv;          // op6,7,12
        cv += (cf[7] * c2 + cf[8] * rs) * INV_M + cf[12] * dv;          // op8,9,13
        dg += cf[0] * dv + (cf[1] * sd + cf[2] * rs + cf[3] * c2) * INV_M
              + cf[4] * tt * INV_M2;                                    // op1..5
        kk += cf[13] * sd * INV_M + cf[14] * tt * INV_M2;               // op14,15
    }
    ws[WS_RV + (n * S_ + s) * M_ + i] = rv + kk + bias[s];
    ws[WS_CV + (n * S_ + s) * M_ + i] = cv;
    ws[WS_DG + (n * S_ + s) * M_ + i] = dg + diag_bias[s];

    // repack dense coefs once: separate contiguous rows for c10 / c11
    if (n == 0 && i < D_) {
        const float* cf = coefs + (i * S_ + s) * 15;
        ws[WS_W10 + i * S_ + s] = cf[9];
        ws[WS_W11 + i * S_ + s] = cf[10];
    }
}

// ---------------- Kernel C: dense part, mirror-pair threads ----------------
// Thread (i,j) of pair {A=(tr,tc), B=(tc,tr)} owns xa=A(i,j), xb=B(j,i):
//   outA(i,j) = sum_d c10*xa + c11*xb ;  outB(j,i) = sum_d c10*xb + c11*xa.
// No LDS, no barriers, 64 v2f-packed accumulators for all 32 s.
// Grid 1152 = 32 n * 36 blocks (28 off-diag pairs + 8 diag tiles), XCD-swizzled.
__global__ __launch_bounds__(256) void eq2_main(const float* __restrict__ x,
                                                const float* __restrict__ ws_,
                                                float* __restrict__ out) {
    const float* ws = (const float*)__builtin_assume_aligned(ws_, 256);
    int lid = blockIdx.x;
    int u   = lid >> 3;               // 0..143
    int n   = (lid & 7) + 8 * (u / 36);
    int b   = u % 36;

    int t = threadIdx.x;
    int i = t >> 4;                   // 0..15
    int j = t & 15;                   // 0..15

    const float* xn = x + (size_t)n * (D_ * MM_);
    const v2f*  w10 = (const v2f*)(ws + WS_W10);   // [D][16] v2f
    const v2f*  w11 = (const v2f*)(ws + WS_W11);
    const float* Rv = ws + WS_RV;
    const float* Cv = ws + WS_CV;
    const float* Dg = ws + WS_DG;

    if (b < 28) {
        // ---- off-diagonal pair ----
        int ti = 0, rem = b;
        while (rem >= 7 - ti) { rem -= 7 - ti; ++ti; }
        int tj = ti + 1 + rem;        // ti < tj
        int Ra = ti * 16, Ca = tj * 16;     // tile A = (ti,tj)

        const float* pA = xn + (Ra + i) * M_ + Ca + j;        // A(i,j)  coalesced
        const float* pB = xn + (Ca + j) * M_ + Ra + i;        // B(j,i)  strided

        v2f accA[16], accB[16];
#pragma unroll
        for (int k = 0; k < 16; ++k) { accA[k] = 0.f; accB[k] = 0.f; }

        float xa0 = pA[0],   xb0 = pB[0];
        float xa1 = pA[MM_], xb1 = pB[MM_];
        for (int d = 0; d < D_; ++d) {
            int dp = (d + 2 < D_) ? d + 2 : D_ - 1;
            float xa2 = pA[(size_t)dp * MM_];
            float xb2 = pB[(size_t)dp * MM_];
            v2f xa = {xa0, xa0}, xb = {xb0, xb0};
            const v2f* wa = w10 + d * 16;     // uniform -> s_load
            const v2f* wb = w11 + d * 16;
#pragma unroll
            for (int k = 0; k < 16; ++k) {
                v2f c0 = wa[k], c1 = wb[k];
                accA[k] = __builtin_elementwise_fma(c0, xa, accA[k]);
                accA[k] = __builtin_elementwise_fma(c1, xb, accA[k]);
                accB[k] = __builtin_elementwise_fma(c0, xb, accB[k]);
                accB[k] = __builtin_elementwise_fma(c1, xa, accB[k]);
            }
            xa0 = xa1; xb0 = xb1; xa1 = xa2; xb1 = xb2;
        }

        int giA = Ra + i, gjA = Ca + j;       // outA position
        int giB = Ca + j, gjB = Ra + i;       // outB position (j,i) of tile B
#pragma unroll
        for (int k = 0; k < 16; ++k) {
#pragma unroll
            for (int h = 0; h < 2; ++h) {
                int s = 2 * k + h;
                int base = (n * S_ + s) * M_;
                float oA = accA[k][h] + Rv[base + giA] + Cv[base + gjA];
                float oB = accB[k][h] + Rv[base + giB] + Cv[base + gjB];
                out[(size_t)base * M_ + giA * M_ + gjA] = oA;
                out[(size_t)base * M_ + giB * M_ + gjB] = oB;
            }
        }
    } else {
        // ---- diagonal tile ----
        int p = b - 28;               // 0..7
        int R = p * 16;

        const float* pA = xn + (R + i) * M_ + R + j;          // T(i,j)
        const float* pB = xn + (R + j) * M_ + R + i;          // T(j,i)

        v2f accA[16];
#pragma unroll
        for (int k = 0; k < 16; ++k) accA[k] = 0.f;

        float xa0 = pA[0],   xb0 = pB[0];
        float xa1 = pA[MM_], xb1 = pB[MM_];
        for (int d = 0; d < D_; ++d) {
            int dp = (d + 2 < D_) ? d + 2 : D_ - 1;
            float xa2 = pA[(size_t)dp * MM_];
            float xb2 = pB[(size_t)dp * MM_];
            v2f xa = {xa0, xa0}, xb = {xb0, xb0};
            const v2f* wa = w10 + d * 16;
            const v2f* wb = w11 + d * 16;
#pragma unroll
            for (int k = 0; k < 16; ++k) {
                accA[k] = __builtin_elementwise_fma(wa[k], xa, accA[k]);
                accA[k] = __builtin_elementwise_fma(wb[k], xb, accA[k]);
            }
            xa0 = xa1; xb0 = xb1; xa1 = xa2; xb1 = xb2;
        }

        int gi = R + i, gj = R + j;
#pragma unroll
        for (int k = 0; k < 16; ++k) {
#pragma unroll
            for (int h = 0; h < 2; ++h) {
                int s = 2 * k + h;
                int base = (n * S_ + s) * M_;
                float oA = accA[k][h] + Rv[base + gi] + Cv[base + gj];
                if (i == j) oA += Dg[base + gi];
                out[(size_t)base * M_ + gi * M_ + gj] = oA;
            }
        }
    }
}

extern "C" void kernel_launch(void* const* d_in, const int* in_sizes, int n_in,
                              void* d_out, int out_size, void* d_ws, size_t ws_size,
                              hipStream_t stream) {
    const float* x         = (const float*)d_in[0];
    const float* coefs     = (const float*)d_in[1];
    const float* bias      = (const float*)d_in[2];
    const float* diag_bias = (const float*)d_in[3];
    float* out = (float*)d_out;
    float* ws  = (float*)d_ws;   // needs ~3.1 MiB

    hipLaunchKernelGGL(eq2_reduce,  dim3(N_ * D_), dim3(256), 0, stream, x, ws);
    hipLaunchKernelGGL(eq2_combine, dim3(N_ * S_), dim3(128), 0, stream, coefs, bias, diag_bias, ws);
    hipLaunchKernelGGL(eq2_main,    dim3(1152), dim3(256), 0, stream, x, ws, out);
}

// Round 5
// 68.121 us; speedup vs baseline: 1.4284x; 1.1968x over previous
//
#include <hip/hip_runtime.h>

// Problem constants (from setup_inputs): N=32, D=32, S=32, B=15, m=128
#define N_ 32
#define D_ 32
#define S_ 32
#define M_ 128
#define MM_ (M_ * M_)
#define INV_M (1.0f / 128.0f)
#define INV_M2 (1.0f / (128.0f * 128.0f))

typedef float v2f __attribute__((ext_vector_type(2)));

// Workspace layout (float offsets). Total 790,528 floats = ~3.02 MiB.
#define WS_ROWSUM  0         // [N*D][128]
#define WS_COLSUM  131072    // [N*D][128]
#define WS_DIAG    262144    // [N*D][128]
#define WS_SUMDIAG 393216    // [N*D]
#define WS_TOT     394240    // [N*D]
#define WS_RV      395264    // [N*S][128]  (includes K + bias)
#define WS_CV      526336    // [N*S][128]
#define WS_DG      657408    // [N*S][128]  (includes diag_bias)
#define WS_W10     788480    // [D][S] c_op10  (s-contiguous rows, 128B aligned)
#define WS_W11     789504    // [D][S] c_op11

// ---------------- Kernel A: per-(n,d) reductions ----------------
__global__ __launch_bounds__(256) void eq2_reduce(const float* __restrict__ x,
                                                  float* __restrict__ ws) {
    int nd = blockIdx.x;              // n*D + d
    int t  = threadIdx.x;
    int g  = t >> 5;                  // row group 0..7 (16 rows each)
    int j4 = t & 31;                  // float4 column group

    const float4* xp = (const float4*)(x + (size_t)nd * MM_);

    float* rowsum  = ws + WS_ROWSUM;
    float* colsum  = ws + WS_COLSUM;
    float* diag    = ws + WS_DIAG;
    float* sumdiag = ws + WS_SUMDIAG;
    float* tot     = ws + WS_TOT;

    float4 cs = {0.f, 0.f, 0.f, 0.f};
    float dsum = 0.f, ttot = 0.f;

    for (int r = 0; r < 16; ++r) {
        int i = g * 16 + r;
        float4 v = xp[i * 32 + j4];
        cs.x += v.x; cs.y += v.y; cs.z += v.z; cs.w += v.w;
        float rp = v.x + v.y + v.z + v.w;
        ttot += rp;
        int c = i - 4 * j4;           // diagonal element if 0..3
        if (c >= 0 && c < 4) {
            float dv = (c == 0) ? v.x : (c == 1) ? v.y : (c == 2) ? v.z : v.w;
            diag[nd * M_ + i] = dv;
            dsum += dv;
        }
        float rs = rp;
        for (int msk = 1; msk < 32; msk <<= 1) rs += __shfl_xor(rs, msk, 64);
        if ((t & 31) == 0) rowsum[nd * M_ + i] = rs;
    }

    __shared__ float4 cs_lds[8][32];
    __shared__ float  red[2][4];
    cs_lds[g][j4] = cs;

    for (int msk = 1; msk < 64; msk <<= 1) {
        dsum += __shfl_xor(dsum, msk, 64);
        ttot += __shfl_xor(ttot, msk, 64);
    }
    int wave = t >> 6, lane = t & 63;
    if (lane == 0) { red[0][wave] = dsum; red[1][wave] = ttot; }
    __syncthreads();

    if (t < 32) {
        float4 a = cs_lds[0][t];
        for (int gg = 1; gg < 8; ++gg) {
            float4 b = cs_lds[gg][t];
            a.x += b.x; a.y += b.y; a.z += b.z; a.w += b.w;
        }
        ((float4*)(colsum + nd * M_))[t] = a;
    }
    if (t == 0) {
        sumdiag[nd] = red[0][0] + red[0][1] + red[0][2] + red[0][3];
        tot[nd]     = red[1][0] + red[1][1] + red[1][2] + red[1][3];
    }
}

// ---------------- Kernel B: contract reductions with coefs over d ----------------
__global__ __launch_bounds__(128) void eq2_combine(const float* __restrict__ coefs,
                                                   const float* __restrict__ bias,
                                                   const float* __restrict__ diag_bias,
                                                   float* __restrict__ ws) {
    int b = blockIdx.x;
    int n = b >> 5, s = b & 31;
    int i = threadIdx.x;              // 0..127

    const float* rowsum  = ws + WS_ROWSUM;
    const float* colsum  = ws + WS_COLSUM;
    const float* diag    = ws + WS_DIAG;
    const float* sumdiag = ws + WS_SUMDIAG;
    const float* tot     = ws + WS_TOT;

    float rv = 0.f, cv = 0.f, dg = 0.f, kk = 0.f;
    for (int d = 0; d < D_; ++d) {
        const float* cf = coefs + (d * S_ + s) * 15;   // uniform -> s_load
        float rs = rowsum[(n * D_ + d) * M_ + i];
        float c2 = colsum[(n * D_ + d) * M_ + i];
        float dv = diag[(n * D_ + d) * M_ + i];
        float sd = sumdiag[n * D_ + d];
        float tt = tot[n * D_ + d];
        rv += (cf[5] * c2 + cf[6] * rs) * INV_M + cf[11] * dv;          // op6,7,12
        cv += (cf[7] * c2 + cf[8] * rs) * INV_M + cf[12] * dv;          // op8,9,13
        dg += cf[0] * dv + (cf[1] * sd + cf[2] * rs + cf[3] * c2) * INV_M
              + cf[4] * tt * INV_M2;                                    // op1..5
        kk += cf[13] * sd * INV_M + cf[14] * tt * INV_M2;               // op14,15
    }
    ws[WS_RV + (n * S_ + s) * M_ + i] = rv + kk + bias[s];
    ws[WS_CV + (n * S_ + s) * M_ + i] = cv;
    ws[WS_DG + (n * S_ + s) * M_ + i] = dg + diag_bias[s];

    // repack dense coefs once: separate contiguous rows for c10 / c11
    if (n == 0 && i < D_) {
        const float* cf = coefs + (i * S_ + s) * 15;
        ws[WS_W10 + i * S_ + s] = cf[9];
        ws[WS_W11 + i * S_ + s] = cf[10];
    }
}

// ---------------- Kernel C: dense part ----------------
// Block = 512 threads = mirror tile-pair {A,B}. Each thread owns ONE position
// p with a single coalesced load stream x_p[d]; accumulates Y_p[s]=sum c10*x,
// Z_p[s]=sum c11*x (32 v2f). d-loop: no LDS, no barriers. Transpose applied
// once in epilogue via LDS: out_p = Y_p + Z_{pT} + rank-1.
// Grid 1024 = 32 n * (28 off-diag pairs + 4 diag pairs), XCD-swizzled.
__global__ __launch_bounds__(512, 2) void eq2_main(const float* __restrict__ x,
                                                   const float* __restrict__ ws_,
                                                   float* __restrict__ out) {
    const float* ws = (const float*)__builtin_assume_aligned(ws_, 256);
    int lid = blockIdx.x;
    int n   = (lid & 7) + 8 * (lid >> 8);
    int b   = (lid >> 3) & 31;

    int AR, AC, BR, BC, diagpair;
    if (b < 28) {
        int ti = 0, rem = b;
        while (rem >= 7 - ti) { rem -= 7 - ti; ++ti; }
        int tj = ti + 1 + rem;        // ti < tj
        AR = ti * 16; AC = tj * 16;   // tile A = (ti,tj)
        BR = tj * 16; BC = ti * 16;   // tile B = (tj,ti) = mirror
        diagpair = 0;
    } else {
        int p = b - 28;               // 0..3
        AR = AC = (2 * p) * 16;       // tile A = diag tile 2p (self-mirror)
        BR = BC = (2 * p + 1) * 16;   // tile B = diag tile 2p+1 (self-mirror)
        diagpair = 1;
    }

    int t    = threadIdx.x;
    int side = t >> 8;                // 0 = A half, 1 = B half
    int i    = (t >> 4) & 15;
    int j    = t & 15;

    int R = side ? BR : AR;
    int C = side ? BC : AC;

    __shared__ float lds_rv[S_][32];
    __shared__ float lds_cv[S_][32];
    __shared__ float lds_dg[S_][32];
    __shared__ float lds_tr[2][8][16][17];

    // ---- stage rank-1 slices into LDS (once) ----
    {
        const float* Rv = ws + WS_RV;
        const float* Cv = ws + WS_CV;
        const float* Dg = ws + WS_DG;
#pragma unroll
        for (int k = 0; k < 4; ++k) {
            int idx = k * 512 + t;        // 0..2047
            int s = idx >> 6, w = idx & 63;
            int arr = w >> 4, o = w & 15;
            int base = (n * S_ + s) * M_;
            float v;
            if      (arr == 0) v = Rv[base + AR + o];
            else if (arr == 1) v = Rv[base + BR + o];
            else if (arr == 2) v = Cv[base + AC + o];
            else               v = Cv[base + BC + o];
            if (arr < 2) lds_rv[s][arr * 16 + o] = v;
            else         lds_cv[s][(arr - 2) * 16 + o] = v;
        }
        if (diagpair) {
#pragma unroll
            for (int k = 0; k < 2; ++k) {
                int idx = k * 512 + t;    // 0..1023
                int s = idx >> 5, w = idx & 31;
                int base = (n * S_ + s) * M_;
                lds_dg[s][w] = Dg[base + (w < 16 ? AR + w : BR + (w - 16))];
            }
        }
    }

    const float* xn = x + (size_t)n * (D_ * MM_);
    const float* px = xn + (R + i) * M_ + C + j;
    const v2f*  w10 = (const v2f*)(ws + WS_W10);   // [D][16] v2f
    const v2f*  w11 = (const v2f*)(ws + WS_W11);

    v2f Y[16], Z[16];
#pragma unroll
    for (int k = 0; k < 16; ++k) { Y[k] = 0.f; Z[k] = 0.f; }

    // depth-3 register pipeline, no barriers in the d-loop
    float x0 = px[0];
    float x1 = px[MM_];
    float x2 = px[2 * MM_];
    __syncthreads();                  // LDS staging visible for epilogue

#pragma unroll 2
    for (int d = 0; d < D_; ++d) {
        int dp = (d + 3 < D_) ? d + 3 : D_ - 1;
        float xnext = px[(size_t)dp * MM_];
        v2f xx = {x0, x0};
        const v2f* wa = w10 + d * 16;     // uniform -> s_load
        const v2f* wb = w11 + d * 16;
#pragma unroll
        for (int k = 0; k < 16; ++k) {
            Y[k] = __builtin_elementwise_fma(wa[k], xx, Y[k]);
            Z[k] = __builtin_elementwise_fma(wb[k], xx, Z[k]);
        }
        x0 = x1; x1 = x2; x2 = xnext;
    }

    // ---- epilogue: LDS transpose of Z in 4 s-groups, add rank-1, store ----
    int rdslot = diagpair ? side : 1 - side;
    int gi = R + i, gj = C + j;
    int roff = side * 16;

    for (int g = 0; g < 4; ++g) {
        if (g) __syncthreads();       // previous group's reads done
#pragma unroll
        for (int ss = 0; ss < 8; ++ss) {
            int s = g * 8 + ss;
            lds_tr[side][ss][i][j] = Z[s >> 1][s & 1];
        }
        __syncthreads();
#pragma unroll
        for (int ss = 0; ss < 8; ++ss) {
            int s = g * 8 + ss;
            int base = (n * S_ + s) * M_;
            float o = Y[s >> 1][s & 1] + lds_tr[rdslot][ss][j][i]
                    + lds_rv[s][roff + i] + lds_cv[s][roff + j];
            if (diagpair && i == j) o += lds_dg[s][roff + i];
            out[(size_t)base * M_ + gi * M_ + gj] = o;
        }
    }
}

extern "C" void kernel_launch(void* const* d_in, const int* in_sizes, int n_in,
                              void* d_out, int out_size, void* d_ws, size_t ws_size,
                              hipStream_t stream) {
    const float* x         = (const float*)d_in[0];
    const float* coefs     = (const float*)d_in[1];
    const float* bias      = (const float*)d_in[2];
    const float* diag_bias = (const float*)d_in[3];
    float* out = (float*)d_out;
    float* ws  = (float*)d_ws;   // needs ~3.1 MiB

    hipLaunchKernelGGL(eq2_reduce,  dim3(N_ * D_), dim3(256), 0, stream, x, ws);
    hipLaunchKernelGGL(eq2_combine, dim3(N_ * S_), dim3(128), 0, stream, coefs, bias, diag_bias, ws);
    hipLaunchKernelGGL(eq2_main,    dim3(1024), dim3(512), 0, stream, x, ws, out);
}

// Round 6
// 53.473 us; speedup vs baseline: 1.8197x; 1.2739x over previous
//
#include <hip/hip_runtime.h>

// Problem constants (from setup_inputs): N=32, D=32, S=32, B=15, m=128
#define N_ 32
#define D_ 32
#define S_ 32
#define M_ 128
#define MM_ (M_ * M_)
#define INV_M (1.0f / 128.0f)
#define INV_M2 (1.0f / (128.0f * 128.0f))

typedef float f32x4 __attribute__((ext_vector_type(4)));
typedef __bf16 bf16x8 __attribute__((ext_vector_type(8)));

// Workspace layout (float offsets).
#define WS_ROWSUM  0         // [N*D][128]
#define WS_COLSUM  131072    // [N*D][128]
#define WS_DIAG    262144    // [N*D][128]
#define WS_SUMDIAG 393216    // [N*D]
#define WS_TOT     394240    // [N*D]
#define WS_RV      395264    // [N*S][128]  (includes K + bias)
#define WS_CV      526336    // [N*S][128]
#define WS_DG      657408    // [N*S][128]  (includes diag_bias)
#define WS_WBF16   788480    // bf16 [64 rows][40] : rows 0-31 = W10[s][d], 32-63 = W11[s][d]

__device__ __forceinline__ unsigned short f2bf(float f) {
    unsigned u = __float_as_uint(f);
    u += 0x7fffu + ((u >> 16) & 1u);          // round-to-nearest-even
    return (unsigned short)(u >> 16);
}

// ---------------- Kernel A: per-(n,d) reductions ----------------
__global__ __launch_bounds__(256) void eq2_reduce(const float* __restrict__ x,
                                                  float* __restrict__ ws) {
    int nd = blockIdx.x;              // n*D + d
    int t  = threadIdx.x;
    int g  = t >> 5;                  // row group 0..7 (16 rows each)
    int j4 = t & 31;                  // float4 column group

    const float4* xp = (const float4*)(x + (size_t)nd * MM_);

    float* rowsum  = ws + WS_ROWSUM;
    float* colsum  = ws + WS_COLSUM;
    float* diag    = ws + WS_DIAG;
    float* sumdiag = ws + WS_SUMDIAG;
    float* tot     = ws + WS_TOT;

    float4 cs = {0.f, 0.f, 0.f, 0.f};
    float dsum = 0.f, ttot = 0.f;

    for (int r = 0; r < 16; ++r) {
        int i = g * 16 + r;
        float4 v = xp[i * 32 + j4];
        cs.x += v.x; cs.y += v.y; cs.z += v.z; cs.w += v.w;
        float rp = v.x + v.y + v.z + v.w;
        ttot += rp;
        int c = i - 4 * j4;           // diagonal element if 0..3
        if (c >= 0 && c < 4) {
            float dv = (c == 0) ? v.x : (c == 1) ? v.y : (c == 2) ? v.z : v.w;
            diag[nd * M_ + i] = dv;
            dsum += dv;
        }
        float rs = rp;
        for (int msk = 1; msk < 32; msk <<= 1) rs += __shfl_xor(rs, msk, 64);
        if ((t & 31) == 0) rowsum[nd * M_ + i] = rs;
    }

    __shared__ float4 cs_lds[8][32];
    __shared__ float  red[2][4];
    cs_lds[g][j4] = cs;

    for (int msk = 1; msk < 64; msk <<= 1) {
        dsum += __shfl_xor(dsum, msk, 64);
        ttot += __shfl_xor(ttot, msk, 64);
    }
    int wave = t >> 6, lane = t & 63;
    if (lane == 0) { red[0][wave] = dsum; red[1][wave] = ttot; }
    __syncthreads();

    if (t < 32) {
        float4 a = cs_lds[0][t];
        for (int gg = 1; gg < 8; ++gg) {
            float4 b = cs_lds[gg][t];
            a.x += b.x; a.y += b.y; a.z += b.z; a.w += b.w;
        }
        ((float4*)(colsum + nd * M_))[t] = a;
    }
    if (t == 0) {
        sumdiag[nd] = red[0][0] + red[0][1] + red[0][2] + red[0][3];
        tot[nd]     = red[1][0] + red[1][1] + red[1][2] + red[1][3];
    }
}

// ---------------- Kernel B: contract reductions with coefs over d ----------------
__global__ __launch_bounds__(128) void eq2_combine(const float* __restrict__ coefs,
                                                   const float* __restrict__ bias,
                                                   const float* __restrict__ diag_bias,
                                                   float* __restrict__ ws) {
    int b = blockIdx.x;
    int n = b >> 5, s = b & 31;
    int i = threadIdx.x;              // 0..127

    const float* rowsum  = ws + WS_ROWSUM;
    const float* colsum  = ws + WS_COLSUM;
    const float* diag    = ws + WS_DIAG;
    const float* sumdiag = ws + WS_SUMDIAG;
    const float* tot     = ws + WS_TOT;

    float rv = 0.f, cv = 0.f, dg = 0.f, kk = 0.f;
    for (int d = 0; d < D_; ++d) {
        const float* cf = coefs + (d * S_ + s) * 15;   // uniform -> s_load
        float rs = rowsum[(n * D_ + d) * M_ + i];
        float c2 = colsum[(n * D_ + d) * M_ + i];
        float dv = diag[(n * D_ + d) * M_ + i];
        float sd = sumdiag[n * D_ + d];
        float tt = tot[n * D_ + d];
        rv += (cf[5] * c2 + cf[6] * rs) * INV_M + cf[11] * dv;          // op6,7,12
        cv += (cf[7] * c2 + cf[8] * rs) * INV_M + cf[12] * dv;          // op8,9,13
        dg += cf[0] * dv + (cf[1] * sd + cf[2] * rs + cf[3] * c2) * INV_M
              + cf[4] * tt * INV_M2;                                    // op1..5
        kk += cf[13] * sd * INV_M + cf[14] * tt * INV_M2;               // op14,15
    }
    ws[WS_RV + (n * S_ + s) * M_ + i] = rv + kk + bias[s];
    ws[WS_CV + (n * S_ + s) * M_ + i] = cv;
    ws[WS_DG + (n * S_ + s) * M_ + i] = dg + diag_bias[s];

    // pack dense coefs once: bf16, transposed to [s][d] rows (stride 40), W11 at rows 32+
    if (n == 0 && i < 32) {
        int d = i;
        unsigned short* wsbf = (unsigned short*)(ws + WS_WBF16);
        const float* cf = coefs + (d * S_ + s) * 15;
        wsbf[s * 40 + d]        = f2bf(cf[9]);
        wsbf[(32 + s) * 40 + d] = f2bf(cf[10]);
    }
}

// ---------------- Kernel C: dense part via MFMA ----------------
// Per n: Y = W10*X, Z = W11*X  (M=32 s, K=32 d, N=positions), bf16 in / f32 acc.
// Block = 512 thr = 8 waves = mirror tile-pair {A=(ti,tj), B=(tj,ti)} (or 2 diag tiles).
// X tiles staged to LDS as bf16 [pos][d] rows; W read as A-frags from global (pre-packed).
// Wave w owns n-tiles 4w..4w+3 (16 positions each): 4 ds_read_b128 + 16 MFMA total.
// Epilogue: out = Y + Z^T(mirror) + Rv + Cv (+Dg), Z exchanged via padded LDS.
__global__ __launch_bounds__(512, 4) void eq2_main(const float* __restrict__ x,
                                                   const float* __restrict__ ws_,
                                                   float* __restrict__ out) {
    const float* ws = (const float*)__builtin_assume_aligned(ws_, 256);
    int lid = blockIdx.x;
    int n   = (lid & 7) + 8 * (lid >> 8);     // XCD-chunked swizzle
    int b   = (lid >> 3) & 31;

    int AR, AC, BR, BC, diagpair;
    if (b < 28) {
        int ti = 0, rem = b;
        while (rem >= 7 - ti) { rem -= 7 - ti; ++ti; }
        int tj = ti + 1 + rem;        // ti < tj
        AR = ti * 16; AC = tj * 16;   // tile A = (ti,tj)
        BR = tj * 16; BC = ti * 16;   // tile B = (tj,ti)
        diagpair = 0;
    } else {
        int p = b - 28;               // 0..3
        AR = AC = (2 * p) * 16;
        BR = BC = (2 * p + 1) * 16;
        diagpair = 1;
    }

    int t    = threadIdx.x;
    int w    = t >> 6;                // wave 0..7
    int lane = t & 63;
    int lg   = lane >> 4;             // 0..3
    int lj   = lane & 15;

    __shared__ __align__(16) unsigned short XB[2][256][40];  // [tile][pos=i*16+j][d] bf16
    __shared__ float trf[8 * 545];                           // Z exchange, padded
    __shared__ float lds_rv[S_][32];
    __shared__ float lds_cv[S_][32];
    __shared__ float lds_dg[S_][32];

    const unsigned short* wsbf = (const unsigned short*)(ws + WS_WBF16);
    const float* xn = x + (size_t)n * (D_ * MM_);

    // ---- A-fragments (W10/W11, two m-tiles) straight from global ----
    bf16x8 A10[2], A11[2];
#pragma unroll
    for (int mt = 0; mt < 2; ++mt) {
        A10[mt] = *(const bf16x8*)(wsbf + (mt * 16 + lj) * 40 + lg * 8);
        A11[mt] = *(const bf16x8*)(wsbf + (32 + mt * 16 + lj) * 40 + lg * 8);
    }

    // ---- stage rank-1 slices ----
    {
        const float* Rv = ws + WS_RV;
        const float* Cv = ws + WS_CV;
        const float* Dg = ws + WS_DG;
#pragma unroll
        for (int k = 0; k < 2; ++k) {
            int idx = k * 512 + t;    // 0..1023
            int s = idx >> 5, q = idx & 31;
            int base = (n * S_ + s) * M_;
            int ro = (q < 16) ? AR + q : BR + (q - 16);
            int co = (q < 16) ? AC + q : BC + (q - 16);
            lds_rv[s][q] = Rv[base + ro];
            lds_cv[s][q] = Cv[base + co];
            if (diagpair) lds_dg[s][q] = Dg[base + ro];
        }
    }

    // ---- stage X tiles to LDS (fp32 -> bf16), [pos][d] rows ----
    {
        int h  = t >> 8;              // d-half
        int ip = (t >> 4) & 15;
        int jp = t & 15;
#pragma unroll
        for (int tt = 0; tt < 2; ++tt) {
            int R = tt ? BR : AR, C = tt ? BC : AC;
            float v[16];
#pragma unroll
            for (int rep = 0; rep < 16; ++rep)
                v[rep] = xn[(size_t)(h * 16 + rep) * MM_ + (R + ip) * M_ + C + jp];
            unsigned u[8];
#pragma unroll
            for (int k2 = 0; k2 < 8; ++k2)
                u[k2] = (unsigned)f2bf(v[2 * k2]) | ((unsigned)f2bf(v[2 * k2 + 1]) << 16);
            unsigned short* dst = &XB[tt][ip * 16 + jp][h * 16];
            uint4 u0; u0.x = u[0]; u0.y = u[1]; u0.z = u[2]; u0.w = u[3];
            uint4 u1; u1.x = u[4]; u1.y = u[5]; u1.z = u[6]; u1.w = u[7];
            ((uint4*)dst)[0] = u0;
            ((uint4*)dst)[1] = u1;
        }
    }

    __syncthreads();

    // ---- MFMA: wave w -> n-tiles 4w..4w+3 ----
    f32x4 aY[4][2], aZ[4][2];
#pragma unroll
    for (int k = 0; k < 4; ++k)
#pragma unroll
        for (int mt = 0; mt < 2; ++mt) { aY[k][mt] = 0.f; aZ[k][mt] = 0.f; }

#pragma unroll
    for (int k = 0; k < 4; ++k) {
        int nt = w * 4 + k;
        int tt = nt >> 4, il = nt & 15;
        bf16x8 Bf = *(const bf16x8*)(&XB[tt][il * 16 + lj][lg * 8]);
        aY[k][0] = __builtin_amdgcn_mfma_f32_16x16x32_bf16(A10[0], Bf, aY[k][0], 0, 0, 0);
        aY[k][1] = __builtin_amdgcn_mfma_f32_16x16x32_bf16(A10[1], Bf, aY[k][1], 0, 0, 0);
        aZ[k][0] = __builtin_amdgcn_mfma_f32_16x16x32_bf16(A11[0], Bf, aZ[k][0], 0, 0, 0);
        aZ[k][1] = __builtin_amdgcn_mfma_f32_16x16x32_bf16(A11[1], Bf, aZ[k][1], 0, 0, 0);
    }

    // ---- epilogue: 4 rounds over acc reg r; Z exchanged via LDS ----
#pragma unroll
    for (int r = 0; r < 4; ++r) {
        if (r) __syncthreads();
#pragma unroll
        for (int k = 0; k < 4; ++k) {
            int nt = w * 4 + k;
            int tt = nt >> 4, il = nt & 15;
#pragma unroll
            for (int mt = 0; mt < 2; ++mt)
                trf[(mt * 4 + lg) * 545 + tt * 272 + il * 17 + lj] = aZ[k][mt][r];
        }
        __syncthreads();
#pragma unroll
        for (int k = 0; k < 4; ++k) {
            int nt = w * 4 + k;
            int tt = nt >> 4, il = nt & 15;
            int ttp = diagpair ? tt : 1 - tt;
            int Rt = tt ? BR : AR, Ct = tt ? BC : AC;
#pragma unroll
            for (int mt = 0; mt < 2; ++mt) {
                int s = mt * 16 + 4 * lg + r;
                float zt = trf[(mt * 4 + lg) * 545 + ttp * 272 + lj * 17 + il];
                float o = aY[k][mt][r] + zt + lds_rv[s][tt * 16 + il] + lds_cv[s][tt * 16 + lj];
                if (diagpair && il == lj) o += lds_dg[s][tt * 16 + il];
                out[(size_t)(n * S_ + s) * MM_ + (Rt + il) * M_ + Ct + lj] = o;
            }
        }
    }
}

extern "C" void kernel_launch(void* const* d_in, const int* in_sizes, int n_in,
                              void* d_out, int out_size, void* d_ws, size_t ws_size,
                              hipStream_t stream) {
    const float* x         = (const float*)d_in[0];
    const float* coefs     = (const float*)d_in[1];
    const float* bias      = (const float*)d_in[2];
    const float* diag_bias = (const float*)d_in[3];
    float* out = (float*)d_out;
    float* ws  = (float*)d_ws;   // needs ~3.1 MiB

    hipLaunchKernelGGL(eq2_reduce,  dim3(N_ * D_), dim3(256), 0, stream, x, ws);
    hipLaunchKernelGGL(eq2_combine, dim3(N_ * S_), dim3(128), 0, stream, coefs, bias, diag_bias, ws);
    hipLaunchKernelGGL(eq2_main,    dim3(1024), dim3(512), 0, stream, x, ws, out);
}